// Round 6
// baseline (251.789 us; speedup 1.0000x reference)
//
#include <hip/hip_runtime.h>
#include <hip/hip_bf16.h>
#include <stdint.h>

using u16 = unsigned short;

typedef __attribute__((ext_vector_type(8))) short bf16x8;
typedef __attribute__((ext_vector_type(4))) float f32x4;

typedef const __attribute__((address_space(1))) unsigned int* gas_t;
typedef __attribute__((address_space(3))) unsigned int* las_t;

__device__ inline void g2l16(const u16* g, u16* l) {
  __builtin_amdgcn_global_load_lds((gas_t)g, (las_t)l, 16, 0, 0);
}

__device__ inline u16 f2b(float x) {
  union { float f; uint32_t u; } v; v.f = x;
  uint32_t r = (v.u + 0x7FFFu + ((v.u >> 16) & 1u)) >> 16;
  return (u16)r;
}
__device__ inline float b2f(u16 b) {
  union { uint32_t u; float f; } v; v.u = ((uint32_t)b) << 16;
  return v.f;
}
__device__ inline float b2f_lo(uint32_t p) {
  union { uint32_t u; float f; } v; v.u = p << 16; return v.f;
}
__device__ inline float b2f_hi(uint32_t p) {
  union { uint32_t u; float f; } v; v.u = p & 0xFFFF0000u; return v.f;
}

__device__ inline void store_out(float* p, float v) { *p = v; }
__device__ inline void store_out(u16* p, float v) { *p = f2b(v); }

#define CFENCE asm volatile("" ::: "memory")

// ---------------------------------------------------------------------------
// Core 128x128 GEMM tile. BK=32, 3-slot LDS ring (48 KB), counted-vmcnt
// prefetch: tile t+2 staged while tile t computes; vmcnt(4) at iter end
// (never 0 in main loop). Chunk perm p(row)=(row^(row>>2))&3 on 64B rows
// keeps ds_read_b128 at <=2-way banks (free). Same involution on stage
// source and read side (both-sides rule).
// ---------------------------------------------------------------------------
template<typename OutT>
__device__ inline void gemm_tile_128(const u16* __restrict__ A,
                                     const u16* __restrict__ Bt,
                                     const float* __restrict__ bias,
                                     OutT* __restrict__ C,
                                     int m0, int n0, int N, int K,
                                     u16* As, u16* Bs)
{
  const int tid  = threadIdx.x;
  const int wave = tid >> 6;
  const int lane = tid & 63;
  const int wm = wave >> 1, wn = wave & 1;
  const int lr = lane & 15;
  const int lq = lane >> 4;
  const int pa8 = ((lq ^ ((lr ^ (lr >> 2)) & 3))) * 8;  // read-side chunk slot

  // staging: 256 threads cover 64 rows x 32 k (4KB) per g2l round
  const int srow = tid >> 2;                    // 0..63
  const int sgc  = (tid & 3) ^ ((srow ^ (srow >> 2)) & 3);
  const u16* gA = A  + (size_t)(m0 + srow) * K + sgc * 8;
  const u16* gB = Bt + (size_t)(n0 + srow) * K + sgc * 8;
  const int ldst = wave * 512;                  // wave-uniform LDS offset (u16)

  f32x4 acc[4][4];
  #pragma unroll
  for (int i = 0; i < 4; ++i)
    #pragma unroll
    for (int j = 0; j < 4; ++j)
      acc[i][j] = (f32x4){0.f, 0.f, 0.f, 0.f};

  // stage tile kt into ring slot `slot` (4 g2l16 per thread)
  auto STAGE = [&](int slot, int kt) {
    const size_t ko = (size_t)kt * 32;
    u16* da = As + slot * 4096 + ldst;
    u16* db = Bs + slot * 4096 + ldst;
    g2l16(gA + ko,                  da);
    g2l16(gA + (size_t)64 * K + ko, da + 2048);
    g2l16(gB + ko,                  db);
    g2l16(gB + (size_t)64 * K + ko, db + 2048);
  };

  const int NT = K >> 5;   // K/32 tiles (>= 3 for K=1024)

  // ---- prologue: stage tiles 0,1; wait tile 0 (8 outstanding -> 4) ----
  STAGE(0, 0);
  STAGE(1, 1);
  asm volatile("s_waitcnt vmcnt(4)" ::: "memory");
  CFENCE;
  __builtin_amdgcn_s_barrier();
  CFENCE;

  int sc = 0;              // slot of tile t
  int sn = 2;              // slot of tile t+2
  for (int t = 0; t < NT; ++t) {
    const bool more = (t + 2 < NT);
    if (more) STAGE(sn, t + 2);      // issue-early: overlaps with compute

    const u16* ab = As + sc * 4096;
    const u16* bb = Bs + sc * 4096;
    bf16x8 af[4], bfr[4];
    #pragma unroll
    for (int im = 0; im < 4; ++im)
      af[im] = *(const bf16x8*)&ab[(wm * 64 + im * 16 + lr) * 32 + pa8];
    #pragma unroll
    for (int in = 0; in < 4; ++in)
      bfr[in] = *(const bf16x8*)&bb[(wn * 64 + in * 16 + lr) * 32 + pa8];

    #pragma unroll
    for (int im = 0; im < 4; ++im)
      #pragma unroll
      for (int in = 0; in < 4; ++in)
        acc[im][in] = __builtin_amdgcn_mfma_f32_16x16x32_bf16(
            af[im], bfr[in], acc[im][in], 0, 0, 0);

    // tile t+1 must be resident before next iter's ds_reads:
    // counted wait (leave tile t+2's 4 loads in flight), then barrier.
    if (more)
      asm volatile("s_waitcnt vmcnt(4)" ::: "memory");
    else
      asm volatile("s_waitcnt vmcnt(0)" ::: "memory");
    CFENCE;
    __builtin_amdgcn_s_barrier();
    CFENCE;

    sc = (sc + 1 == 3) ? 0 : sc + 1;
    sn = (sn + 1 == 3) ? 0 : sn + 1;
  }

  #pragma unroll
  for (int im = 0; im < 4; ++im) {
    const int mbase = m0 + wm * 64 + im * 16 + lq * 4;
    #pragma unroll
    for (int in = 0; in < 4; ++in) {
      const int ncol = n0 + wn * 64 + in * 16 + lr;
      #pragma unroll
      for (int r = 0; r < 4; ++r) {
        const int m = mbase + r;
        store_out(C + (size_t)m * N + ncol, acc[im][in][r] + bias[m]);
      }
    }
  }
}

// keys [4096x4096] (by<32) and Q [1024x4096] (by>=32) in one dispatch.
__global__ __launch_bounds__(256)
void gemm_keys_q(const u16* __restrict__ WIb, const u16* __restrict__ IT,
                 const float* __restrict__ bim, u16* __restrict__ KEYS,
                 const u16* __restrict__ WLb, const u16* __restrict__ PT,
                 const float* __restrict__ bL, u16* __restrict__ Qb)
{
  __shared__ u16 As[3 * 128 * 32];   // 24 KB
  __shared__ u16 Bs[3 * 128 * 32];   // 24 KB
  const int by = blockIdx.y;
  const bool keys = (by < 32);
  const u16*   A    = keys ? WIb : WLb;
  const u16*   Bt   = keys ? IT  : PT;
  const float* bias = keys ? bim : bL;
  u16*         C    = keys ? KEYS : Qb;
  const int m0 = (by & 31) * 128;
  const int n0 = blockIdx.x * 128;
  gemm_tile_128<u16>(A, Bt, bias, C, m0, n0, 4096, 1024, As, Bs);
}

// final fp32 GEMM: out = W_f * fused + b_f, 128x128 tiles (grid 32x8).
__global__ __launch_bounds__(256)
void gemm_f(const u16* __restrict__ A, const u16* __restrict__ Bt,
            const float* __restrict__ bias, float* __restrict__ C)
{
  __shared__ u16 As[3 * 128 * 32];
  __shared__ u16 Bs[3 * 128 * 32];
  gemm_tile_128<float>(A, Bt, bias, C, blockIdx.y * 128, blockIdx.x * 128,
                       4096, 1024, As, Bs);
}

// ---------------------------------------------------------------------------
// Prep: P,I fp32 -> bf16 transposed (64x64 tiles, float4 in / ushort4 out,
// LDS pad 66) PLUS 3 weight casts, one dispatch.
// ---------------------------------------------------------------------------
__global__ __launch_bounds__(256)
void prep(const float* __restrict__ P, u16* __restrict__ PT,
          const float* __restrict__ I, u16* __restrict__ IT,
          const float4* __restrict__ wim, const float4* __restrict__ wl,
          const float4* __restrict__ wf, ushort4* __restrict__ wimb,
          ushort4* __restrict__ wlb, ushort4* __restrict__ wfb)
{
  const int bid = blockIdx.x;
  if (bid < 2048) {
    const int z   = bid >> 10;          // 0: P, 1: I
    const int rem = bid & 1023;
    const int ct  = rem & 63;           // 64 col-tiles (N=4096)
    const int rt  = rem >> 6;           // 16 row-tiles (R=1024)
    const float* in = z ? I : P;
    u16* out = z ? IT : PT;
    __shared__ u16 tile[64][66];
    const int r0 = rt * 64, c0 = ct * 64;
    const int tr  = threadIdx.x >> 4;   // 0..15
    const int tc4 = threadIdx.x & 15;   // 0..15 (x4 elements)
    #pragma unroll
    for (int it = 0; it < 4; ++it) {
      const int r = it * 16 + tr;
      const float4 v = *(const float4*)&in[(size_t)(r0 + r) * 4096 + c0 + tc4 * 4];
      ushort4 o;
      o.x = f2b(v.x); o.y = f2b(v.y); o.z = f2b(v.z); o.w = f2b(v.w);
      *(ushort4*)&tile[r][tc4 * 4] = o;
    }
    __syncthreads();
    #pragma unroll
    for (int it = 0; it < 4; ++it) {
      const int c = it * 16 + tr;
      ushort4 o;
      o.x = tile[tc4 * 4 + 0][c];
      o.y = tile[tc4 * 4 + 1][c];
      o.z = tile[tc4 * 4 + 2][c];
      o.w = tile[tc4 * 4 + 3][c];
      *(ushort4*)&out[(size_t)(c0 + c) * 1024 + r0 + tc4 * 4] = o;
    }
  } else {
    int i = (bid - 2048) * 256 + threadIdx.x;
    const float4* src; ushort4* dst;
    if (i < 1048576)      { src = wim; dst = wimb; }
    else if (i < 1310720) { src = wl;  dst = wlb;  i -= 1048576; }
    else                  { src = wf;  dst = wfb;  i -= 1310720; }
    const float4 v = src[i];
    ushort4 o;
    o.x = f2b(v.x); o.y = f2b(v.y); o.z = f2b(v.z); o.w = f2b(v.w);
    dst[i] = o;
  }
}

// bf16 [R x C] -> bf16 [C x R], 64x64 tiles, ushort4 both sides, pad 66.
__global__ __launch_bounds__(256)
void transpose_u16(const u16* __restrict__ in, u16* __restrict__ out,
                   int R, int C)
{
  __shared__ u16 tile[64][66];
  const int c0 = blockIdx.x * 64, r0 = blockIdx.y * 64;
  const int tr  = threadIdx.x >> 4;
  const int tc4 = threadIdx.x & 15;
  #pragma unroll
  for (int it = 0; it < 4; ++it) {
    const int r = it * 16 + tr;
    *(ushort4*)&tile[r][tc4 * 4] =
        *(const ushort4*)&in[(size_t)(r0 + r) * C + c0 + tc4 * 4];
  }
  __syncthreads();
  #pragma unroll
  for (int it = 0; it < 4; ++it) {
    const int c = it * 16 + tr;
    ushort4 o;
    o.x = tile[tc4 * 4 + 0][c];
    o.y = tile[tc4 * 4 + 1][c];
    o.z = tile[tc4 * 4 + 2][c];
    o.w = tile[tc4 * 4 + 3][c];
    *(ushort4*)&out[(size_t)(c0 + c) * R + r0 + tc4 * 4] = o;
  }
}

// part[cy][h][n] = (1/32) * sum_{c in 16-chunk cy} Q[c][n]*keys[h*1024+c][n]
__global__ __launch_bounds__(256)
void score_partial(const u16* __restrict__ keys, const u16* __restrict__ Qb,
                   float* __restrict__ part)
{
  const int n  = blockIdx.x * 1024 + threadIdx.x * 4;
  const int c0 = blockIdx.y * 16;
  float s[4][4];
  #pragma unroll
  for (int h = 0; h < 4; ++h)
    #pragma unroll
    for (int e = 0; e < 4; ++e) s[h][e] = 0.f;

  for (int c = c0; c < c0 + 16; ++c) {
    const uint2 qv = *(const uint2*)&Qb[(size_t)c * 4096 + n];
    const float q0 = b2f_lo(qv.x), q1 = b2f_hi(qv.x);
    const float q2 = b2f_lo(qv.y), q3 = b2f_hi(qv.y);
    #pragma unroll
    for (int h = 0; h < 4; ++h) {
      const uint2 kv = *(const uint2*)&keys[((size_t)((h << 10) + c)) * 4096 + n];
      s[h][0] = fmaf(q0, b2f_lo(kv.x), s[h][0]);
      s[h][1] = fmaf(q1, b2f_hi(kv.x), s[h][1]);
      s[h][2] = fmaf(q2, b2f_lo(kv.y), s[h][2]);
      s[h][3] = fmaf(q3, b2f_hi(kv.y), s[h][3]);
    }
  }
  #pragma unroll
  for (int h = 0; h < 4; ++h) {
    float4 o;
    o.x = s[h][0] * 0.03125f; o.y = s[h][1] * 0.03125f;
    o.z = s[h][2] * 0.03125f; o.w = s[h][3] * 0.03125f;
    *(float4*)&part[((size_t)(blockIdx.y * 4 + h)) * 4096 + n] = o;
  }
}

// reduce 64 partial chunks + softmax over 4 heads -> weightmap
__global__ __launch_bounds__(256)
void softmax_h(const float* __restrict__ part, float* __restrict__ wmap)
{
  __shared__ float red[4][4][64];
  const int nl = threadIdx.x & 63;
  const int cq = threadIdx.x >> 6;        // 0..3
  const int n  = blockIdx.x * 64 + nl;
  float s[4] = {0.f, 0.f, 0.f, 0.f};
  #pragma unroll
  for (int k = 0; k < 16; ++k) {
    const int cy = cq * 16 + k;
    const float* p = part + (size_t)cy * 16384 + n;
    s[0] += p[0]; s[1] += p[4096]; s[2] += p[8192]; s[3] += p[12288];
  }
  #pragma unroll
  for (int h = 0; h < 4; ++h) red[cq][h][nl] = s[h];
  __syncthreads();
  if (threadIdx.x < 64) {
    const float t0 = red[0][0][nl] + red[1][0][nl] + red[2][0][nl] + red[3][0][nl];
    const float t1 = red[0][1][nl] + red[1][1][nl] + red[2][1][nl] + red[3][1][nl];
    const float t2 = red[0][2][nl] + red[1][2][nl] + red[2][2][nl] + red[3][2][nl];
    const float t3 = red[0][3][nl] + red[1][3][nl] + red[2][3][nl] + red[3][3][nl];
    const float m = fmaxf(fmaxf(t0, t1), fmaxf(t2, t3));
    const float e0 = expf(t0 - m), e1 = expf(t1 - m);
    const float e2 = expf(t2 - m), e3 = expf(t3 - m);
    const float inv = 1.f / (e0 + e1 + e2 + e3);
    wmap[n] = e0 * inv; wmap[4096 + n] = e1 * inv;
    wmap[8192 + n] = e2 * inv; wmap[12288 + n] = e3 * inv;
  }
}

// z = sum_h w[h][n]*keys[h][c][n]; t = z + Q; LayerNorm over n; bf16 out.
__global__ __launch_bounds__(256)
void z_ln(const u16* __restrict__ keys, const u16* __restrict__ Qb,
          const float* __restrict__ w, const float* __restrict__ g,
          const float* __restrict__ bb, u16* __restrict__ fused)
{
  const int c  = blockIdx.x;
  const int tx = threadIdx.x;
  float t[16];
  float s = 0.f, s2 = 0.f;
  #pragma unroll
  for (int j = 0; j < 2; ++j) {
    const int n = tx * 8 + j * 2048;
    const uint4 qv = *(const uint4*)&Qb[(size_t)c * 4096 + n];
    float z[8] = {0.f,0.f,0.f,0.f,0.f,0.f,0.f,0.f};
    #pragma unroll
    for (int h = 0; h < 4; ++h) {
      const uint4 kv = *(const uint4*)&keys[((size_t)((h << 10) + c)) * 4096 + n];
      const float4 w0 = *(const float4*)&w[h * 4096 + n];
      const float4 w1 = *(const float4*)&w[h * 4096 + n + 4];
      z[0] = fmaf(w0.x, b2f_lo(kv.x), z[0]);
      z[1] = fmaf(w0.y, b2f_hi(kv.x), z[1]);
      z[2] = fmaf(w0.z, b2f_lo(kv.y), z[2]);
      z[3] = fmaf(w0.w, b2f_hi(kv.y), z[3]);
      z[4] = fmaf(w1.x, b2f_lo(kv.z), z[4]);
      z[5] = fmaf(w1.y, b2f_hi(kv.z), z[5]);
      z[6] = fmaf(w1.z, b2f_lo(kv.w), z[6]);
      z[7] = fmaf(w1.w, b2f_hi(kv.w), z[7]);
    }
    const uint32_t qs[4] = {qv.x, qv.y, qv.z, qv.w};
    #pragma unroll
    for (int e = 0; e < 4; ++e) {
      const float v0 = z[2 * e]     + b2f_lo(qs[e]);
      const float v1 = z[2 * e + 1] + b2f_hi(qs[e]);
      t[8 * j + 2 * e]     = v0;
      t[8 * j + 2 * e + 1] = v1;
      s += v0 + v1;
      s2 = fmaf(v0, v0, fmaf(v1, v1, s2));
    }
  }
  #pragma unroll
  for (int o = 32; o > 0; o >>= 1) {
    s  += __shfl_down(s, o);
    s2 += __shfl_down(s2, o);
  }
  __shared__ float rbuf[8];
  const int wave = tx >> 6, lane = tx & 63;
  if (lane == 0) { rbuf[wave] = s; rbuf[4 + wave] = s2; }
  __syncthreads();
  s  = rbuf[0] + rbuf[1] + rbuf[2] + rbuf[3];
  s2 = rbuf[4] + rbuf[5] + rbuf[6] + rbuf[7];
  const float mu  = s * (1.f / 4096.f);
  const float var = s2 * (1.f / 4096.f) - mu * mu;
  const float rs  = rsqrtf(var + 1e-5f);
  #pragma unroll
  for (int j = 0; j < 2; ++j) {
    const int n = tx * 8 + j * 2048;
    #pragma unroll
    for (int q4 = 0; q4 < 2; ++q4) {
      const float4 gv = *(const float4*)&g[n + 4 * q4];
      const float4 bv = *(const float4*)&bb[n + 4 * q4];
      ushort4 o;
      o.x = f2b((t[8 * j + 4 * q4]     - mu) * rs * gv.x + bv.x);
      o.y = f2b((t[8 * j + 4 * q4 + 1] - mu) * rs * gv.y + bv.y);
      o.z = f2b((t[8 * j + 4 * q4 + 2] - mu) * rs * gv.z + bv.z);
      o.w = f2b((t[8 * j + 4 * q4 + 3] - mu) * rs * gv.w + bv.w);
      *(ushort4*)&fused[(size_t)c * 4096 + n + 4 * q4] = o;
    }
  }
}

extern "C" void kernel_launch(void* const* d_in, const int* in_sizes, int n_in,
                              void* d_out, int out_size, void* d_ws, size_t ws_size,
                              hipStream_t stream)
{
  const float* P   = (const float*)d_in[0];
  const float* I   = (const float*)d_in[1];
  const float* Wim = (const float*)d_in[2];
  const float* bim = (const float*)d_in[3];
  const float* WL  = (const float*)d_in[4];
  const float* bL  = (const float*)d_in[5];
  const float* lng = (const float*)d_in[6];
  const float* lnb = (const float*)d_in[7];
  const float* Wf  = (const float*)d_in[8];
  const float* bf_ = (const float*)d_in[9];
  float* out = (float*)d_out;

  char* ws = (char*)d_ws;
  u16*   PT     = (u16*)(ws + 0);                      //  8 MB [4096 x 1024]
  u16*   IT     = (u16*)(ws + (size_t)8  * 1048576);   //  8 MB
  u16*   WLb    = (u16*)(ws + (size_t)16 * 1048576);   //  2 MB
  u16*   WIb    = (u16*)(ws + (size_t)18 * 1048576);   //  8 MB
  u16*   WFb    = (u16*)(ws + (size_t)26 * 1048576);   //  2 MB
  u16*   Qb     = (u16*)(ws + (size_t)28 * 1048576);   //  8 MB [1024 x 4096]
  u16*   KEYS   = (u16*)(ws + (size_t)36 * 1048576);   // 32 MB [4096 x 4096]
  // PART aliases PT: PT is dead after gemm_keys_q, PART written after it.
  float* PART   = (float*)(ws + 0);                    //  4 MB [64][4][4096]
  u16*   FUSED  = (u16*)(ws + (size_t)70 * 1048576);   //  8 MB [1024 x 4096]
  u16*   FUSEDT = (u16*)(ws + (size_t)78 * 1048576);   //  8 MB [4096 x 1024]

  const dim3 b256(256);

  // all input casts/transposes in one dispatch (8192 blocks, vectorized)
  prep<<<8192, b256, 0, stream>>>(P, PT, I, IT,
                                  (const float4*)Wim, (const float4*)WL,
                                  (const float4*)Wf, (ushort4*)WIb,
                                  (ushort4*)WLb, (ushort4*)WFb);

  // keys [4096x4096] + Q [1024x4096], both bf16, one dispatch (1280 blocks)
  gemm_keys_q<<<dim3(32, 40), b256, 0, stream>>>(WIb, IT, bim, KEYS,
                                                 WLb, PT, bL, Qb);

  // score partials (256 blocks, no atomics) -> reduce+softmax -> weightmap
  score_partial<<<dim3(4, 64), b256, 0, stream>>>(KEYS, Qb, PART);
  float* wmap = out + (size_t)1024 * 4096;
  softmax_h<<<64, b256, 0, stream>>>(PART, wmap);

  // z + residual + LayerNorm -> bf16 (8-wide), then transpose for final GEMM
  z_ln<<<1024, b256, 0, stream>>>(KEYS, Qb, wmap, lng, lnb, FUSED);
  transpose_u16<<<dim3(64, 16), b256, 0, stream>>>(FUSED, FUSEDT, 1024, 4096);

  // out = W_f * fused + b_f  [1024 x 4096] fp32, 128x128 tiles
  gemm_f<<<dim3(32, 8), b256, 0, stream>>>(WFb, FUSEDT, bf_, out);
}

// Round 8
// 208.917 us; speedup vs baseline: 1.2052x; 1.2052x over previous
//
#include <hip/hip_runtime.h>
#include <hip/hip_bf16.h>
#include <stdint.h>

using u16 = unsigned short;

typedef __attribute__((ext_vector_type(8))) short bf16x8;
typedef __attribute__((ext_vector_type(4))) float f32x4;

typedef const __attribute__((address_space(1))) unsigned int* gas_t;
typedef __attribute__((address_space(3))) unsigned int* las_t;

__device__ inline void g2l16(const u16* g, u16* l) {
  __builtin_amdgcn_global_load_lds((gas_t)g, (las_t)l, 16, 0, 0);
}

__device__ inline u16 f2b(float x) {
  union { float f; uint32_t u; } v; v.f = x;
  uint32_t r = (v.u + 0x7FFFu + ((v.u >> 16) & 1u)) >> 16;
  return (u16)r;
}
__device__ inline float b2f(u16 b) {
  union { uint32_t u; float f; } v; v.u = ((uint32_t)b) << 16;
  return v.f;
}
__device__ inline float b2f_lo(uint32_t p) {
  union { uint32_t u; float f; } v; v.u = p << 16; return v.f;
}
__device__ inline float b2f_hi(uint32_t p) {
  union { uint32_t u; float f; } v; v.u = p & 0xFFFF0000u; return v.f;
}

__device__ inline void store_out(float* p, float v) { *p = v; }
__device__ inline void store_out(u16* p, float v) { *p = f2b(v); }

// ---------------------------------------------------------------------------
// Champion 128x128 GEMM core. BK=64, XOR-swizzled LDS (0 conflicts, proven).
// Computes acc only; epilogue is kernel-specific.
// ---------------------------------------------------------------------------
__device__ inline void gemm_core_128(const u16* __restrict__ A,
                                     const u16* __restrict__ Bt,
                                     int m0, int n0, int K,
                                     u16* As, u16* Bs, f32x4 (&acc)[4][4])
{
  const int tid  = threadIdx.x;
  const int wave = tid >> 6;
  const int lane = tid & 63;
  const int wm = wave >> 1, wn = wave & 1;
  const int lr = lane & 15;
  const int lq = lane >> 4;
  const int x7 = lr & 7;

  const int srow = tid >> 3;
  const int sgc  = (tid & 7) ^ (srow & 7);
  const u16* gA = A  + (size_t)(m0 + srow) * K + sgc * 8;
  const u16* gB = Bt + (size_t)(n0 + srow) * K + sgc * 8;
  u16* dstA = As + wave * 512;
  u16* dstB = Bs + wave * 512;

  #pragma unroll
  for (int i = 0; i < 4; ++i)
    #pragma unroll
    for (int j = 0; j < 4; ++j)
      acc[i][j] = (f32x4){0.f, 0.f, 0.f, 0.f};

  for (int k0 = 0; k0 < K; k0 += 64) {
    #pragma unroll
    for (int s = 0; s < 4; ++s) {
      g2l16(gA + (size_t)(s * 32) * K + k0, dstA + s * 2048);
      g2l16(gB + (size_t)(s * 32) * K + k0, dstB + s * 2048);
    }
    __syncthreads();

    #pragma unroll
    for (int ks = 0; ks < 2; ++ks) {
      const int pa = (ks * 4 + lq) ^ x7;
      bf16x8 af[4], bfr[4];
      #pragma unroll
      for (int im = 0; im < 4; ++im)
        af[im] = *(const bf16x8*)&As[(wm * 64 + im * 16 + lr) * 64 + pa * 8];
      #pragma unroll
      for (int in = 0; in < 4; ++in)
        bfr[in] = *(const bf16x8*)&Bs[(wn * 64 + in * 16 + lr) * 64 + pa * 8];

      #pragma unroll
      for (int im = 0; im < 4; ++im)
        #pragma unroll
        for (int in = 0; in < 4; ++in)
          acc[im][in] = __builtin_amdgcn_mfma_f32_16x16x32_bf16(
              af[im], bfr[in], acc[im][in], 0, 0, 0);
    }
    __syncthreads();
  }
}

// ---------------------------------------------------------------------------
// keys GEMM with FUSED score epilogue. Grid (32, 32): m0 = by*128 covers all
// 4 heads (h = by>>3). Epilogue: write bf16 KEYS tile AND accumulate the
// 128-c partial of score[h][n] = sum_c keys[h,c,n]*Q[c,n]/32 from the fp32
// accumulators (Q is L2-hot bf16). shfl-reduce over lq => 256 atomics/block.
// ---------------------------------------------------------------------------
__global__ __launch_bounds__(256)
void gemm_keys_score(const u16* __restrict__ WIb, const u16* __restrict__ IT,
                     const float* __restrict__ bim, u16* __restrict__ KEYS,
                     const u16* __restrict__ Qb, float* __restrict__ score)
{
  __shared__ u16 As[128 * 64];
  __shared__ u16 Bs[128 * 64];
  const int m0 = blockIdx.y * 128;
  const int n0 = blockIdx.x * 128;
  f32x4 acc[4][4];
  gemm_core_128(WIb, IT, m0, n0, 1024, As, Bs, acc);

  const int tid  = threadIdx.x;
  const int wave = tid >> 6;
  const int lane = tid & 63;
  const int wm = wave >> 1, wn = wave & 1;
  const int lr = lane & 15;
  const int lq = lane >> 4;
  const int h  = m0 >> 10;

  float sp[4] = {0.f, 0.f, 0.f, 0.f};
  #pragma unroll
  for (int im = 0; im < 4; ++im) {
    const int mbase = m0 + wm * 64 + im * 16 + lq * 4;
    #pragma unroll
    for (int in = 0; in < 4; ++in) {
      const int ncol = n0 + wn * 64 + in * 16 + lr;
      #pragma unroll
      for (int r = 0; r < 4; ++r) {
        const int m = mbase + r;
        const float v = acc[im][in][r] + bim[m];
        KEYS[(size_t)m * 4096 + ncol] = f2b(v);
        sp[in] = fmaf(v, b2f(Qb[(size_t)(m & 1023) * 4096 + ncol]), sp[in]);
      }
    }
  }
  #pragma unroll
  for (int in = 0; in < 4; ++in) {
    float v = sp[in];
    v += __shfl_down(v, 32);
    v += __shfl_down(v, 16);
    if (lane < 16)
      atomicAdd(&score[h * 4096 + n0 + wn * 64 + in * 16 + lane],
                v * 0.03125f);
  }
}

// ---------------------------------------------------------------------------
// 64x128 tile GEMM (champion). Used for Q = WL*P^T (bf16 out) and the final
// fp32 GEMM. Grid (32,16) = 512 blocks.
// ---------------------------------------------------------------------------
template<typename OutT>
__global__ __launch_bounds__(256)
void gemm_bt_64(const u16* __restrict__ A, const u16* __restrict__ Bt,
                const float* __restrict__ bias, OutT* __restrict__ C,
                int M, int N, int K)
{
  __shared__ u16 As[64 * 64];
  __shared__ u16 Bs[128 * 64];

  const int tid  = threadIdx.x;
  const int wave = tid >> 6;
  const int lane = tid & 63;
  const int lr = lane & 15;
  const int lq = lane >> 4;
  const int x7 = lr & 7;

  const int m0 = blockIdx.y * 64;
  const int n0 = blockIdx.x * 128;

  const int srow = tid >> 3;
  const int sgc  = (tid & 7) ^ (srow & 7);
  const u16* gA = A  + (size_t)(m0 + srow) * K + sgc * 8;
  const u16* gB = Bt + (size_t)(n0 + srow) * K + sgc * 8;
  u16* dstA = As + wave * 512;
  u16* dstB = Bs + wave * 512;

  f32x4 acc[4][2];
  #pragma unroll
  for (int i = 0; i < 4; ++i)
    #pragma unroll
    for (int j = 0; j < 2; ++j)
      acc[i][j] = (f32x4){0.f, 0.f, 0.f, 0.f};

  for (int k0 = 0; k0 < K; k0 += 64) {
    #pragma unroll
    for (int s = 0; s < 2; ++s)
      g2l16(gA + (size_t)(s * 32) * K + k0, dstA + s * 2048);
    #pragma unroll
    for (int s = 0; s < 4; ++s)
      g2l16(gB + (size_t)(s * 32) * K + k0, dstB + s * 2048);
    __syncthreads();

    #pragma unroll
    for (int ks = 0; ks < 2; ++ks) {
      const int pa = (ks * 4 + lq) ^ x7;
      bf16x8 af[4], bfr[2];
      #pragma unroll
      for (int im = 0; im < 4; ++im)
        af[im] = *(const bf16x8*)&As[(im * 16 + lr) * 64 + pa * 8];
      #pragma unroll
      for (int in = 0; in < 2; ++in)
        bfr[in] = *(const bf16x8*)&Bs[(wave * 32 + in * 16 + lr) * 64 + pa * 8];

      #pragma unroll
      for (int im = 0; im < 4; ++im)
        #pragma unroll
        for (int in = 0; in < 2; ++in)
          acc[im][in] = __builtin_amdgcn_mfma_f32_16x16x32_bf16(
              af[im], bfr[in], acc[im][in], 0, 0, 0);
    }
    __syncthreads();
  }

  #pragma unroll
  for (int im = 0; im < 4; ++im) {
    const int mbase = m0 + im * 16 + lq * 4;
    #pragma unroll
    for (int in = 0; in < 2; ++in) {
      const int ncol = n0 + wave * 32 + in * 16 + lr;
      #pragma unroll
      for (int r = 0; r < 4; ++r) {
        const int m = mbase + r;
        store_out(C + (size_t)m * N + ncol, acc[im][in][r] + bias[m]);
      }
    }
  }
}

// ---------------------------------------------------------------------------
// Prep: P,I fp32->bf16 transposed  PLUS  3 weight casts (champion 32x33).
// ---------------------------------------------------------------------------
__global__ __launch_bounds__(256)
void prep(const float* __restrict__ P, u16* __restrict__ PT,
          const float* __restrict__ I, u16* __restrict__ IT,
          const float4* __restrict__ wim, const float4* __restrict__ wl,
          const float4* __restrict__ wf, ushort4* __restrict__ wimb,
          ushort4* __restrict__ wlb, ushort4* __restrict__ wfb)
{
  const int bid = blockIdx.x;
  if (bid < 8192) {
    const int z   = bid >> 12;          // 0: P, 1: I
    const int rem = bid & 4095;
    const int bx  = rem & 127;
    const int byy = rem >> 7;
    const float* in = z ? I : P;
    u16* out = z ? IT : PT;
    __shared__ u16 tile[32][33];
    const int c0 = bx * 32, r0 = byy * 32;
    const int tx = threadIdx.x & 31, ty = threadIdx.x >> 5;
    #pragma unroll
    for (int k = 0; k < 4; ++k)
      tile[ty + 8 * k][tx] = f2b(in[(size_t)(r0 + ty + 8 * k) * 4096 + c0 + tx]);
    __syncthreads();
    #pragma unroll
    for (int k = 0; k < 4; ++k)
      out[(size_t)(c0 + ty + 8 * k) * 1024 + r0 + tx] = tile[tx][ty + 8 * k];
  } else {
    int i = (bid - 8192) * 256 + threadIdx.x;
    const float4* src; ushort4* dst;
    if (i < 1048576)      { src = wim; dst = wimb; }
    else if (i < 1310720) { src = wl;  dst = wlb;  i -= 1048576; }
    else                  { src = wf;  dst = wfb;  i -= 1310720; }
    const float4 v = src[i];
    ushort4 o;
    o.x = f2b(v.x); o.y = f2b(v.y); o.z = f2b(v.z); o.w = f2b(v.w);
    dst[i] = o;
  }
}

// bf16 [R x C] -> bf16 [C x R]  (champion 32x33)
__global__ __launch_bounds__(256)
void transpose_u16(const u16* __restrict__ in, u16* __restrict__ out,
                   int R, int C)
{
  __shared__ u16 tile[32][33];
  const int c0 = blockIdx.x * 32, r0 = blockIdx.y * 32;
  const int tx = threadIdx.x & 31, ty = threadIdx.x >> 5;
  #pragma unroll
  for (int k = 0; k < 4; ++k)
    tile[ty + 8 * k][tx] = in[(size_t)(r0 + ty + 8 * k) * C + c0 + tx];
  __syncthreads();
  #pragma unroll
  for (int k = 0; k < 4; ++k)
    out[(size_t)(c0 + ty + 8 * k) * R + r0 + tx] = tile[tx][ty + 8 * k];
}

// softmax over 4 heads -> weightmap (champion version)
__global__ __launch_bounds__(256)
void softmax_h(const float* __restrict__ score, float* __restrict__ wmap)
{
  const int n = blockIdx.x * 256 + threadIdx.x;
  const float s0 = score[n], s1 = score[4096 + n];
  const float s2 = score[8192 + n], s3 = score[12288 + n];
  const float m = fmaxf(fmaxf(s0, s1), fmaxf(s2, s3));
  const float e0 = expf(s0 - m), e1 = expf(s1 - m);
  const float e2 = expf(s2 - m), e3 = expf(s3 - m);
  const float inv = 1.f / (e0 + e1 + e2 + e3);
  wmap[n] = e0 * inv; wmap[4096 + n] = e1 * inv;
  wmap[8192 + n] = e2 * inv; wmap[12288 + n] = e3 * inv;
}

// z = sum_h w[h][n]*keys[h][c][n]; t = z + Q; LayerNorm over n; bf16 out.
__global__ __launch_bounds__(256)
void z_ln(const u16* __restrict__ keys, const u16* __restrict__ Qb,
          const float* __restrict__ w, const float* __restrict__ g,
          const float* __restrict__ bb, u16* __restrict__ fused)
{
  const int c  = blockIdx.x;
  const int tx = threadIdx.x;
  float t[16];
  float s = 0.f, s2 = 0.f;
  #pragma unroll
  for (int j = 0; j < 2; ++j) {
    const int n = tx * 8 + j * 2048;
    const uint4 qv = *(const uint4*)&Qb[(size_t)c * 4096 + n];
    float z[8] = {0.f,0.f,0.f,0.f,0.f,0.f,0.f,0.f};
    #pragma unroll
    for (int h = 0; h < 4; ++h) {
      const uint4 kv = *(const uint4*)&keys[((size_t)((h << 10) + c)) * 4096 + n];
      const float4 w0 = *(const float4*)&w[h * 4096 + n];
      const float4 w1 = *(const float4*)&w[h * 4096 + n + 4];
      z[0] = fmaf(w0.x, b2f_lo(kv.x), z[0]);
      z[1] = fmaf(w0.y, b2f_hi(kv.x), z[1]);
      z[2] = fmaf(w0.z, b2f_lo(kv.y), z[2]);
      z[3] = fmaf(w0.w, b2f_hi(kv.y), z[3]);
      z[4] = fmaf(w1.x, b2f_lo(kv.z), z[4]);
      z[5] = fmaf(w1.y, b2f_hi(kv.z), z[5]);
      z[6] = fmaf(w1.z, b2f_lo(kv.w), z[6]);
      z[7] = fmaf(w1.w, b2f_hi(kv.w), z[7]);
    }
    const uint32_t qs[4] = {qv.x, qv.y, qv.z, qv.w};
    #pragma unroll
    for (int e = 0; e < 4; ++e) {
      const float v0 = z[2 * e]     + b2f_lo(qs[e]);
      const float v1 = z[2 * e + 1] + b2f_hi(qs[e]);
      t[8 * j + 2 * e]     = v0;
      t[8 * j + 2 * e + 1] = v1;
      s += v0 + v1;
      s2 = fmaf(v0, v0, fmaf(v1, v1, s2));
    }
  }
  #pragma unroll
  for (int o = 32; o > 0; o >>= 1) {
    s  += __shfl_down(s, o);
    s2 += __shfl_down(s2, o);
  }
  __shared__ float rbuf[8];
  const int wave = tx >> 6, lane = tx & 63;
  if (lane == 0) { rbuf[wave] = s; rbuf[4 + wave] = s2; }
  __syncthreads();
  s  = rbuf[0] + rbuf[1] + rbuf[2] + rbuf[3];
  s2 = rbuf[4] + rbuf[5] + rbuf[6] + rbuf[7];
  const float mu  = s * (1.f / 4096.f);
  const float var = s2 * (1.f / 4096.f) - mu * mu;
  const float rs  = rsqrtf(var + 1e-5f);
  #pragma unroll
  for (int j = 0; j < 2; ++j) {
    const int n = tx * 8 + j * 2048;
    #pragma unroll
    for (int q4 = 0; q4 < 2; ++q4) {
      const float4 gv = *(const float4*)&g[n + 4 * q4];
      const float4 bv = *(const float4*)&bb[n + 4 * q4];
      ushort4 o;
      o.x = f2b((t[8 * j + 4 * q4]     - mu) * rs * gv.x + bv.x);
      o.y = f2b((t[8 * j + 4 * q4 + 1] - mu) * rs * gv.y + bv.y);
      o.z = f2b((t[8 * j + 4 * q4 + 2] - mu) * rs * gv.z + bv.z);
      o.w = f2b((t[8 * j + 4 * q4 + 3] - mu) * rs * gv.w + bv.w);
      *(ushort4*)&fused[(size_t)c * 4096 + n + 4 * q4] = o;
    }
  }
}

extern "C" void kernel_launch(void* const* d_in, const int* in_sizes, int n_in,
                              void* d_out, int out_size, void* d_ws, size_t ws_size,
                              hipStream_t stream)
{
  const float* P   = (const float*)d_in[0];
  const float* I   = (const float*)d_in[1];
  const float* Wim = (const float*)d_in[2];
  const float* bim = (const float*)d_in[3];
  const float* WL  = (const float*)d_in[4];
  const float* bL  = (const float*)d_in[5];
  const float* lng = (const float*)d_in[6];
  const float* lnb = (const float*)d_in[7];
  const float* Wf  = (const float*)d_in[8];
  const float* bf_ = (const float*)d_in[9];
  float* out = (float*)d_out;

  char* ws = (char*)d_ws;
  u16*   PT     = (u16*)(ws + 0);                      //  8 MB [4096 x 1024]
  u16*   IT     = (u16*)(ws + (size_t)8  * 1048576);   //  8 MB
  u16*   WLb    = (u16*)(ws + (size_t)16 * 1048576);   //  2 MB
  u16*   WIb    = (u16*)(ws + (size_t)18 * 1048576);   //  8 MB
  u16*   WFb    = (u16*)(ws + (size_t)26 * 1048576);   //  2 MB
  u16*   Qb     = (u16*)(ws + (size_t)28 * 1048576);   //  8 MB [1024 x 4096]
  u16*   KEYS   = (u16*)(ws + (size_t)36 * 1048576);   // 32 MB [4096 x 4096]
  float* SCORE  = (float*)(ws + (size_t)68 * 1048576); // 64 KB [4 x 4096]
  u16*   FUSED  = (u16*)(ws + (size_t)70 * 1048576);   //  8 MB [1024 x 4096]
  u16*   FUSEDT = (u16*)(ws + (size_t)78 * 1048576);   //  8 MB [4096 x 1024]

  const dim3 b256(256);

  // all input casts/transposes in one dispatch (champion)
  prep<<<14336, b256, 0, stream>>>(P, PT, I, IT,
                                   (const float4*)Wim, (const float4*)WL,
                                   (const float4*)Wf, (ushort4*)WIb,
                                   (ushort4*)WLb, (ushort4*)WFb);

  // Q = W_L * P^T  [1024 x 4096] bf16 (proven 64x128 kernel, 512 blocks)
  gemm_bt_64<u16><<<dim3(32, 16), b256, 0, stream>>>(WLb, PT, bL, Qb,
                                                     1024, 4096, 1024);

  // keys [4096x4096] bf16 with FUSED score accumulation (1024 blocks)
  hipMemsetAsync(SCORE, 0, 4 * 4096 * sizeof(float), stream);
  gemm_keys_score<<<dim3(32, 32), b256, 0, stream>>>(WIb, IT, bim, KEYS,
                                                     Qb, SCORE);

  // softmax over heads -> weightmap
  float* wmap = out + (size_t)1024 * 4096;
  softmax_h<<<16, b256, 0, stream>>>(SCORE, wmap);

  // z + residual + LayerNorm -> bf16, then transpose for final GEMM
  z_ln<<<1024, b256, 0, stream>>>(KEYS, Qb, wmap, lng, lnb, FUSED);
  transpose_u16<<<dim3(128, 32), b256, 0, stream>>>(FUSED, FUSEDT, 1024, 4096);

  // out = W_f * fused + b_f  [1024 x 4096] fp32
  gemm_bt_64<float><<<dim3(32, 16), b256, 0, stream>>>(WFb, FUSEDT, bf_, out,
                                                       1024, 4096, 1024);
}